// Round 20
// baseline (166.397 us; speedup 1.0000x reference)
//
#include <hip/hip_runtime.h>
#include <hip/hip_bf16.h>

typedef __attribute__((ext_vector_type(4))) float f32x4;
typedef __attribute__((ext_vector_type(8))) short s16x8;

#define C_DIM 256
#define H_DIM 128
#define W_DIM 512
#define HW    (H_DIM * W_DIM)      /* 65536  */
#define CHW   (C_DIM * HW)         /* 16777216 */
#define WS_NEED (2ull * 128 * 512 * 256 * 2)   /* 67108864 B: bf16 [bh][n][k] */

__device__ __forceinline__ unsigned short f2bf(float f) {
    return __builtin_bit_cast(unsigned short, __float2bfloat16(f));
}

__device__ __forceinline__ void gl_lds16(const void* g, void* l) {
    __builtin_amdgcn_global_load_lds(
        (const __attribute__((address_space(1))) void*)g,
        (__attribute__((address_space(3))) void*)l, 16, 0, 0);
}

// ---------------- K1: transpose+convert img2 -> ws bf16 [bh][n=512][k=256] ----
// ~HBM-roofline: reads f32 coalesced, LDS-staged transpose, writes bf16
// k-contiguous.
__global__ __launch_bounds__(256) void transpose_kernel(
    const float* __restrict__ img2, unsigned short* __restrict__ bws)
{
    __shared__ unsigned short tile[64][65];
    const int t = threadIdx.x;
    const int d = blockIdx.x;               // 8192 = 2b*128h*4cb*8wb
    const int cb = d & 3, wb = (d >> 2) & 7, bh = d >> 5;
    const int b = bh >> 7, h = bh & 127;
    const float* src = img2 + (size_t)b * CHW + (size_t)h * W_DIM
                            + (size_t)(cb * 64) * HW + wb * 64;
    {
        const int c = t >> 2, w0 = (t & 3) << 4;
        const float* p = src + (size_t)c * HW + w0;
        #pragma unroll
        for (int i = 0; i < 16; i += 4) {
            f32x4 v = *(const f32x4*)(p + i);
            #pragma unroll
            for (int j = 0; j < 4; ++j) tile[c][w0 + i + j] = f2bf(v[j]);
        }
    }
    __syncthreads();
    {
        const int n_l = t >> 2, c4 = (t & 3) << 4;
        unsigned short vals[16];
        #pragma unroll
        for (int i = 0; i < 16; ++i) vals[i] = tile[c4 + i][n_l];
        unsigned short* dst = bws + ((size_t)bh * 512 + wb * 64 + n_l) * 256 + cb * 64 + c4;
        *(s16x8*)(dst)     = *(s16x8*)&vals[0];
        *(s16x8*)(dst + 8) = *(s16x8*)&vals[8];
    }
}

// ---------------- K2 (R18 skeleton, XCD swizzle REMOVED — T1 A/B in the
// L3-fit regime per m160): 512 thr, 64 w1 x 512 w2, 8 waves of 64x64.
// LDS = A 32K + B 32K (wave-private single-buffer slices) -> 2 WGs/CU.
// No K-loop barriers; gl_lds B staging, split LDS drain, T5 setprio.
// Swapped MFMA (D.row = w2): softmax axis lane-local -> cheap epilogue.
__global__ __launch_bounds__(512, 4) void costvol_kernel(
    const float* __restrict__ img1, const unsigned short* __restrict__ bws,
    const float* __restrict__ intri1,
    const float* __restrict__ extri1, const float* __restrict__ extri2,
    float* __restrict__ out)
{
    __shared__ __align__(16) unsigned char smem[65536];   // A 32K | B 32K
    unsigned short* Alds = (unsigned short*)smem;         // [64][256] bf16 swizzled

    const int t = threadIdx.x;
    const int d = blockIdx.x;                              // grid 2048
    // identity mapping: consecutive blocks (same bh) round-robin across XCDs;
    // ws is L3-resident so 8-way B reuse is served by L3 (m160 L3-fit regime)
    const int bh    = d >> 3;
    const int w1blk = d & 7;                               // 0..7
    const int b = bh >> 7, h = bh & 127;
    const int w1base = w1blk * 64;

    const int wv = t >> 6, lane = t & 63;
    const int lrow = lane & 15, hq = lane >> 4;

    // B staging, wave-private: wave wv owns w2 cols [64wv,64wv+64).
    // Slice = 64 rows x 32 k bf16 = 4KB; 4 gl_lds16 per kc. Source pre-swizzled
    // (m173 pattern): for u=i*64+lane: r=i*16+(lane>>2), k8=lane&3,
    // swz = (r>>1)&3 = (lane>>3)&3.
    const unsigned short* bsrc0 =
        bws + ((size_t)bh * 512 + 64 * wv + (lane >> 2)) * 256
            + 8 * ((lane & 3) ^ ((lane >> 3) & 3));
    unsigned char* const bdst = smem + 32768 + wv * 4096;   // wave slice base

    // prologue: issue B stage for kc=0 (in flight under A staging)
    #pragma unroll
    for (int i = 0; i < 4; ++i)
        gl_lds16(bsrc0 + i * 4096, bdst + i * 1024);

    // ---- stage A once, scaled by 1/16 (exact in bf16): [m=64][k=256],
    // 16B-block XOR swizzle
    const float* i1 = img1 + (size_t)b * CHW + (size_t)h * W_DIM;
    {
        const int c    = t >> 1;                 // 0..255
        const int wseg = (t & 1) << 5;           // 0 or 32
        const float* src = i1 + (size_t)c * HW + (size_t)(w1base + wseg);
        #pragma unroll
        for (int i0 = 0; i0 < 32; i0 += 4) {
            f32x4 v = *(const f32x4*)(src + i0);
            #pragma unroll
            for (int j = 0; j < 4; ++j) {
                const int w = wseg + i0 + j;
                Alds[w * 256 + ((((c >> 3) ^ (w & 15)) << 3) | (c & 7))] = f2bf(v[j] * 0.0625f);
            }
        }
    }
    __syncthreads();   // drains vmcnt too: B kc=0 landed + A visible to all waves

    f32x4 acc[4][4] = {};   // [w2t][w1t]

    // per-lane B read offsets (bytes) within this wave's 4KB slice:
    // local row = 16*w2t + lrow, k-group slot = hq ^ ((lrow>>1)&3)
    int boff[4];
    #pragma unroll
    for (int w2t = 0; w2t < 4; ++w2t)
        boff[w2t] = (16 * w2t + lrow) * 64 + 16 * (hq ^ ((lrow >> 1) & 3));

    #pragma unroll
    for (int kc = 0; kc < 8; ++kc) {
        // B-frag reads FIRST (their completion gates the DMA WAR) ...
        s16x8 bfr[4], afr[4];
        #pragma unroll
        for (int w2t = 0; w2t < 4; ++w2t)
            bfr[w2t] = *(const s16x8*)(bdst + boff[w2t]);
        // pin issue order: all 4 B-reads precede the A-reads
        __builtin_amdgcn_sched_barrier(0);
        #pragma unroll
        for (int w1t = 0; w1t < 4; ++w1t) {
            const int row = 16 * w1t + lrow;
            const int kb  = (kc << 2) + hq;
            afr[w1t] = *(const s16x8*)&Alds[row * 256 + ((kb ^ (row & 15)) << 3)];
        }
        // DS ops complete in-order: <=4 outstanding => the 4 B-reads landed.
        // (A-reads may still be in flight; the DMA only touches the B slice.)
        asm volatile("s_waitcnt lgkmcnt(4)" ::: "memory");
        __builtin_amdgcn_sched_barrier(0);
        // issue kc+1 DMA into the SAME wave-private slice (WAR safe)
        if (kc < 7) {
            #pragma unroll
            for (int i = 0; i < 4; ++i)
                gl_lds16(bsrc0 + (kc + 1) * 32 + i * 4096, bdst + i * 1024);
        }
        __builtin_amdgcn_sched_barrier(0);
        // MFMAs while the DMA flies; setprio favors the compute-phase wave
        // over co-resident staging-phase waves (independent pipelines -> T5 regime)
        __builtin_amdgcn_s_setprio(1);
        #pragma unroll
        for (int w2t = 0; w2t < 4; ++w2t)
            #pragma unroll
            for (int w1t = 0; w1t < 4; ++w1t)
                acc[w2t][w1t] = __builtin_amdgcn_mfma_f32_16x16x32_bf16(
                    bfr[w2t], afr[w1t], acc[w2t][w1t], 0, 0, 0);
        __builtin_amdgcn_s_setprio(0);
        // DMA must land before next iteration's slice reads
        if (kc < 7)
            asm volatile("s_waitcnt vmcnt(0)" ::: "memory");
    }

    __syncthreads();   // all waves done; A region reusable for reduction

    // ---- epilogue: lane-local over w2 (w2 = 64*wv + 16*w2t + 4*hq + r,
    //                w1 = 16*w1t + lrow), 2-step cross-hq butterfly.
    float (*red)[64][3] = (float(*)[64][3])smem;   // [8 waves][64 rows][Se,Sei,Me]
    #pragma unroll
    for (int w1t = 0; w1t < 4; ++w1t) {
        const int w1l = 16 * w1t + lrow;
        const int w1g = w1base + w1l;
        float Se = 0.f, Sei = 0.f, Me = 0.f;
        #pragma unroll
        for (int w2t = 0; w2t < 4; ++w2t) {
            #pragma unroll
            for (int r = 0; r < 4; ++r) {
                const int w2 = 64 * wv + 16 * w2t + 4 * hq + r;
                const float e = __expf(acc[w2t][w1t][r]);   // vol pre-scaled by 1/16
                Se += e;
                if (w2 <= w1g) { Sei += e * (float)w2; Me = fmaxf(Me, e); }
            }
        }
        Se  += __shfl_xor(Se, 16, 64);  Se  += __shfl_xor(Se, 32, 64);
        Sei += __shfl_xor(Sei, 16, 64); Sei += __shfl_xor(Sei, 32, 64);
        Me = fmaxf(Me, __shfl_xor(Me, 16, 64)); Me = fmaxf(Me, __shfl_xor(Me, 32, 64));
        if (hq == 0) {
            red[wv][w1l][0] = Se;
            red[wv][w1l][1] = Sei;
            red[wv][w1l][2] = Me;
        }
    }
    __syncthreads();

    if (t < 64) {
        const int row = t;
        float Se = 0.f, Sei = 0.f, Me = 0.f;
        #pragma unroll
        for (int q = 0; q < 8; ++q) {
            Se  += red[q][row][0];
            Sei += red[q][row][1];
            Me   = fmaxf(Me, red[q][row][2]);
        }
        const int w1g = w1base + row;
        const float corresp = Sei / Se;            // soft-argmax (masked num, full denom)
        const float conf    = Me / Se;             // max of post-softmax masked prob
        float disp = fabsf(corresp - (float)w1g) * (1.0f / 512.0f);
        disp = fmaxf(disp, 0.1f);
        const float fx = intri1[b * 9];
        const float dx = extri1[b * 16 + 3]  - extri2[b * 16 + 3];
        const float dy = extri1[b * 16 + 7]  - extri2[b * 16 + 7];
        const float dz = extri1[b * 16 + 11] - extri2[b * 16 + 11];
        const float bl = sqrtf(dx * dx + dy * dy + dz * dz);
        const float depth = fx * bl / disp;
        const int oidx = b * HW + h * W_DIM + w1g;
        out[oidx]          = depth;
        out[2 * HW + oidx] = conf;                 // confidence block at B*H*W = 131072
    }
}

// ---------------- Fallback (R2 kernel, proven): direct f32 B loads, no ws
__global__ __launch_bounds__(512, 4) void costvol_fallback(
    const float* __restrict__ img1, const float* __restrict__ img2,
    const float* __restrict__ intri1,
    const float* __restrict__ extri1, const float* __restrict__ extri2,
    float* __restrict__ out)
{
    __shared__ __align__(16) unsigned char smem[32768];
    unsigned short* Alds = (unsigned short*)smem;
    const int t = threadIdx.x;
    const int d = blockIdx.x;
    const int win = d >> 6, pos = d & 63;
    const int bh    = win * 8 + (pos & 7);
    const int w1blk = pos >> 3;
    const int b = bh >> 7, h = bh & 127;
    const int w1base = w1blk * 64;
    const float* i1 = img1 + (size_t)b * CHW + (size_t)h * W_DIM;
    const float* i2 = img2 + (size_t)b * CHW + (size_t)h * W_DIM;
    {
        const int c    = t >> 1;
        const int wseg = (t & 1) << 5;
        const float* src = i1 + (size_t)c * HW + (size_t)(w1base + wseg);
        #pragma unroll
        for (int i0 = 0; i0 < 32; i0 += 4) {
            f32x4 v = *(const f32x4*)(src + i0);
            #pragma unroll
            for (int j = 0; j < 4; ++j) {
                const int w = wseg + i0 + j;
                Alds[w * 256 + ((((c >> 3) ^ (w & 15)) << 3) | (c & 7))] = f2bf(v[j]);
            }
        }
    }
    __syncthreads();
    const int wn = t >> 6, lane = t & 63;
    const int lrow = lane & 15, hq = lane >> 4;
    const float* pb[4];
    #pragma unroll
    for (int ct = 0; ct < 4; ++ct)
        pb[ct] = i2 + (size_t)(8 * hq) * HW + (64 * wn + 16 * ct + lrow);
    f32x4 acc[4][4] = {};
    for (int kc = 0; kc < 8; ++kc) {
        s16x8 afr[4];
        #pragma unroll
        for (int rt = 0; rt < 4; ++rt) {
            const int row = 16 * rt + lrow;
            const int kb  = (kc << 2) + hq;
            afr[rt] = *(const s16x8*)&Alds[row * 256 + ((kb ^ (row & 15)) << 3)];
        }
        #pragma unroll
        for (int ct = 0; ct < 4; ++ct) {
            const float* p = pb[ct] + (size_t)(32 * kc) * HW;
            float f[8];
            #pragma unroll
            for (int j = 0; j < 8; ++j) f[j] = p[(size_t)j * HW];
            s16x8 bfr;
            #pragma unroll
            for (int j = 0; j < 8; ++j) bfr[j] = (short)f2bf(f[j]);
            #pragma unroll
            for (int rt = 0; rt < 4; ++rt)
                acc[rt][ct] = __builtin_amdgcn_mfma_f32_16x16x32_bf16(afr[rt], bfr, acc[rt][ct], 0, 0, 0);
        }
    }
    __syncthreads();
    float (*red)[64][3] = (float(*)[64][3])smem;
    #pragma unroll
    for (int rt = 0; rt < 4; ++rt) {
        #pragma unroll
        for (int r = 0; r < 4; ++r) {
            const int row = 16 * rt + 4 * hq + r;
            const int w1g = w1base + row;
            float Se = 0.f, Sei = 0.f, Me = 0.f;
            #pragma unroll
            for (int ct = 0; ct < 4; ++ct) {
                const int col = 64 * wn + 16 * ct + lrow;
                const float e = __expf(acc[rt][ct][r] * 0.0625f);
                Se += e;
                if (col <= w1g) { Sei += e * (float)col; Me = fmaxf(Me, e); }
            }
            #pragma unroll
            for (int m = 1; m < 16; m <<= 1) {
                Se  += __shfl_xor(Se,  m, 64);
                Sei += __shfl_xor(Sei, m, 64);
                Me   = fmaxf(Me, __shfl_xor(Me, m, 64));
            }
            if (lrow == 0) { red[wn][row][0] = Se; red[wn][row][1] = Sei; red[wn][row][2] = Me; }
        }
    }
    __syncthreads();
    if (t < 64) {
        const int row = t;
        float Se = 0.f, Sei = 0.f, Me = 0.f;
        #pragma unroll
        for (int q = 0; q < 8; ++q) {
            Se += red[q][row][0]; Sei += red[q][row][1]; Me = fmaxf(Me, red[q][row][2]);
        }
        const int w1g = w1base + row;
        const float corresp = Sei / Se;
        const float conf    = Me / Se;
        float disp = fabsf(corresp - (float)w1g) * (1.0f / 512.0f);
        disp = fmaxf(disp, 0.1f);
        const float fx = intri1[b * 9];
        const float dx = extri1[b * 16 + 3]  - extri2[b * 16 + 3];
        const float dy = extri1[b * 16 + 7]  - extri2[b * 16 + 7];
        const float dz = extri1[b * 16 + 11] - extri2[b * 16 + 11];
        const float bl = sqrtf(dx * dx + dy * dy + dz * dz);
        const int oidx = b * HW + h * W_DIM + w1g;
        out[oidx]          = fx * bl / disp;
        out[2 * HW + oidx] = conf;
    }
}

extern "C" void kernel_launch(void* const* d_in, const int* in_sizes, int n_in,
                              void* d_out, int out_size, void* d_ws, size_t ws_size,
                              hipStream_t stream) {
    const float* img1   = (const float*)d_in[0];
    const float* img2   = (const float*)d_in[1];
    const float* intri1 = (const float*)d_in[2];
    const float* extri1 = (const float*)d_in[4];
    const float* extri2 = (const float*)d_in[5];
    if (ws_size >= WS_NEED) {
        unsigned short* bws = (unsigned short*)d_ws;
        transpose_kernel<<<dim3(8192), dim3(256), 0, stream>>>(img2, bws);
        costvol_kernel<<<dim3(2048), dim3(512), 0, stream>>>(
            img1, bws, intri1, extri1, extri2, (float*)d_out);
    } else {
        costvol_fallback<<<dim3(2048), dim3(512), 0, stream>>>(
            img1, img2, intri1, extri1, extri2, (float*)d_out);
    }
}

// Round 21
// 121.509 us; speedup vs baseline: 1.3694x; 1.3694x over previous
//
#include <hip/hip_runtime.h>
#include <hip/hip_bf16.h>

typedef __attribute__((ext_vector_type(4))) float f32x4;
typedef __attribute__((ext_vector_type(8))) short s16x8;

#define C_DIM 256
#define H_DIM 128
#define W_DIM 512
#define HW    (H_DIM * W_DIM)      /* 65536  */
#define CHW   (C_DIM * HW)         /* 16777216 */
#define WS_NEED (2ull * 128 * 512 * 256 * 2)   /* 67108864 B: bf16 [bh][n][k] */

__device__ __forceinline__ unsigned short f2bf(float f) {
    return __builtin_bit_cast(unsigned short, __float2bfloat16(f));
}

__device__ __forceinline__ void gl_lds16(const void* g, void* l) {
    __builtin_amdgcn_global_load_lds(
        (const __attribute__((address_space(1))) void*)g,
        (__attribute__((address_space(3))) void*)l, 16, 0, 0);
}

// ---------------- K1: transpose+convert img2 -> ws bf16 [bh][n=512][k=256] ----
// ~HBM-roofline: reads f32 coalesced, LDS-staged transpose, writes bf16
// k-contiguous.
__global__ __launch_bounds__(256) void transpose_kernel(
    const float* __restrict__ img2, unsigned short* __restrict__ bws)
{
    __shared__ unsigned short tile[64][65];
    const int t = threadIdx.x;
    const int d = blockIdx.x;               // 8192 = 2b*128h*4cb*8wb
    const int cb = d & 3, wb = (d >> 2) & 7, bh = d >> 5;
    const int b = bh >> 7, h = bh & 127;
    const float* src = img2 + (size_t)b * CHW + (size_t)h * W_DIM
                            + (size_t)(cb * 64) * HW + wb * 64;
    {
        const int c = t >> 2, w0 = (t & 3) << 4;
        const float* p = src + (size_t)c * HW + w0;
        #pragma unroll
        for (int i = 0; i < 16; i += 4) {
            f32x4 v = *(const f32x4*)(p + i);
            #pragma unroll
            for (int j = 0; j < 4; ++j) tile[c][w0 + i + j] = f2bf(v[j]);
        }
    }
    __syncthreads();
    {
        const int n_l = t >> 2, c4 = (t & 3) << 4;
        unsigned short vals[16];
        #pragma unroll
        for (int i = 0; i < 16; ++i) vals[i] = tile[c4 + i][n_l];
        unsigned short* dst = bws + ((size_t)bh * 512 + wb * 64 + n_l) * 256 + cb * 64 + c4;
        *(s16x8*)(dst)     = *(s16x8*)&vals[0];
        *(s16x8*)(dst + 8) = *(s16x8*)&vals[8];
    }
}

// ---------------- K2 (FINAL == R18): 512 thr, 64 w1 x 512 w2, 8 waves of
// 64x64. LDS = A 32K + B 32K (wave-private single-buffer slices) -> 2 WGs/CU.
// XCD swizzle (T1) is ESSENTIAL here: without it FETCH 100->434 MB (R20).
// No K-loop barriers: 8 independent per-wave pipelines; gl_lds B staging
// with split LDS drain (lgkmcnt(4)) + T5 setprio around the MFMA cluster.
// Swapped MFMA (D.row = w2): softmax axis lane-local -> cheap epilogue.
__global__ __launch_bounds__(512, 4) void costvol_kernel(
    const float* __restrict__ img1, const unsigned short* __restrict__ bws,
    const float* __restrict__ intri1,
    const float* __restrict__ extri1, const float* __restrict__ extri2,
    float* __restrict__ out)
{
    __shared__ __align__(16) unsigned char smem[65536];   // A 32K | B 32K
    unsigned short* Alds = (unsigned short*)smem;         // [64][256] bf16 swizzled

    const int t = threadIdx.x;
    const int d = blockIdx.x;                              // grid 2048
    // XCD swizzle: the 8 WGs sharing (b,h) get ids stride-8 apart -> same XCD
    const int win = d >> 6, pos = d & 63;
    const int bh    = win * 8 + (pos & 7);
    const int w1blk = pos >> 3;                            // 0..7
    const int b = bh >> 7, h = bh & 127;
    const int w1base = w1blk * 64;

    const int wv = t >> 6, lane = t & 63;
    const int lrow = lane & 15, hq = lane >> 4;

    // B staging, wave-private: wave wv owns w2 cols [64wv,64wv+64).
    // Slice = 64 rows x 32 k bf16 = 4KB; 4 gl_lds16 per kc. Source pre-swizzled
    // (m173 pattern): for u=i*64+lane: r=i*16+(lane>>2), k8=lane&3,
    // swz = (r>>1)&3 = (lane>>3)&3.
    const unsigned short* bsrc0 =
        bws + ((size_t)bh * 512 + 64 * wv + (lane >> 2)) * 256
            + 8 * ((lane & 3) ^ ((lane >> 3) & 3));
    unsigned char* const bdst = smem + 32768 + wv * 4096;   // wave slice base

    // prologue: issue B stage for kc=0 (in flight under A staging)
    #pragma unroll
    for (int i = 0; i < 4; ++i)
        gl_lds16(bsrc0 + i * 4096, bdst + i * 1024);

    // ---- stage A once, scaled by 1/16 (exact in bf16): [m=64][k=256],
    // 16B-block XOR swizzle
    const float* i1 = img1 + (size_t)b * CHW + (size_t)h * W_DIM;
    {
        const int c    = t >> 1;                 // 0..255
        const int wseg = (t & 1) << 5;           // 0 or 32
        const float* src = i1 + (size_t)c * HW + (size_t)(w1base + wseg);
        #pragma unroll
        for (int i0 = 0; i0 < 32; i0 += 4) {
            f32x4 v = *(const f32x4*)(src + i0);
            #pragma unroll
            for (int j = 0; j < 4; ++j) {
                const int w = wseg + i0 + j;
                Alds[w * 256 + ((((c >> 3) ^ (w & 15)) << 3) | (c & 7))] = f2bf(v[j] * 0.0625f);
            }
        }
    }
    __syncthreads();   // drains vmcnt too: B kc=0 landed + A visible to all waves

    f32x4 acc[4][4] = {};   // [w2t][w1t]

    // per-lane B read offsets (bytes) within this wave's 4KB slice:
    // local row = 16*w2t + lrow, k-group slot = hq ^ ((lrow>>1)&3)
    int boff[4];
    #pragma unroll
    for (int w2t = 0; w2t < 4; ++w2t)
        boff[w2t] = (16 * w2t + lrow) * 64 + 16 * (hq ^ ((lrow >> 1) & 3));

    #pragma unroll
    for (int kc = 0; kc < 8; ++kc) {
        // B-frag reads FIRST (their completion gates the DMA WAR) ...
        s16x8 bfr[4], afr[4];
        #pragma unroll
        for (int w2t = 0; w2t < 4; ++w2t)
            bfr[w2t] = *(const s16x8*)(bdst + boff[w2t]);
        // pin issue order: all 4 B-reads precede the A-reads
        __builtin_amdgcn_sched_barrier(0);
        #pragma unroll
        for (int w1t = 0; w1t < 4; ++w1t) {
            const int row = 16 * w1t + lrow;
            const int kb  = (kc << 2) + hq;
            afr[w1t] = *(const s16x8*)&Alds[row * 256 + ((kb ^ (row & 15)) << 3)];
        }
        // DS ops complete in-order: <=4 outstanding => the 4 B-reads landed.
        // (A-reads may still be in flight; the DMA only touches the B slice.)
        asm volatile("s_waitcnt lgkmcnt(4)" ::: "memory");
        __builtin_amdgcn_sched_barrier(0);
        // issue kc+1 DMA into the SAME wave-private slice (WAR safe)
        if (kc < 7) {
            #pragma unroll
            for (int i = 0; i < 4; ++i)
                gl_lds16(bsrc0 + (kc + 1) * 32 + i * 4096, bdst + i * 1024);
        }
        __builtin_amdgcn_sched_barrier(0);
        // MFMAs while the DMA flies; setprio favors the compute-phase wave
        // over co-resident staging-phase waves (independent pipelines -> T5 regime)
        __builtin_amdgcn_s_setprio(1);
        #pragma unroll
        for (int w2t = 0; w2t < 4; ++w2t)
            #pragma unroll
            for (int w1t = 0; w1t < 4; ++w1t)
                acc[w2t][w1t] = __builtin_amdgcn_mfma_f32_16x16x32_bf16(
                    bfr[w2t], afr[w1t], acc[w2t][w1t], 0, 0, 0);
        __builtin_amdgcn_s_setprio(0);
        // DMA must land before next iteration's slice reads
        if (kc < 7)
            asm volatile("s_waitcnt vmcnt(0)" ::: "memory");
    }

    __syncthreads();   // all waves done; A region reusable for reduction

    // ---- epilogue: lane-local over w2 (w2 = 64*wv + 16*w2t + 4*hq + r,
    //                w1 = 16*w1t + lrow), 2-step cross-hq butterfly.
    float (*red)[64][3] = (float(*)[64][3])smem;   // [8 waves][64 rows][Se,Sei,Me]
    #pragma unroll
    for (int w1t = 0; w1t < 4; ++w1t) {
        const int w1l = 16 * w1t + lrow;
        const int w1g = w1base + w1l;
        float Se = 0.f, Sei = 0.f, Me = 0.f;
        #pragma unroll
        for (int w2t = 0; w2t < 4; ++w2t) {
            #pragma unroll
            for (int r = 0; r < 4; ++r) {
                const int w2 = 64 * wv + 16 * w2t + 4 * hq + r;
                const float e = __expf(acc[w2t][w1t][r]);   // vol pre-scaled by 1/16
                Se += e;
                if (w2 <= w1g) { Sei += e * (float)w2; Me = fmaxf(Me, e); }
            }
        }
        Se  += __shfl_xor(Se, 16, 64);  Se  += __shfl_xor(Se, 32, 64);
        Sei += __shfl_xor(Sei, 16, 64); Sei += __shfl_xor(Sei, 32, 64);
        Me = fmaxf(Me, __shfl_xor(Me, 16, 64)); Me = fmaxf(Me, __shfl_xor(Me, 32, 64));
        if (hq == 0) {
            red[wv][w1l][0] = Se;
            red[wv][w1l][1] = Sei;
            red[wv][w1l][2] = Me;
        }
    }
    __syncthreads();

    if (t < 64) {
        const int row = t;
        float Se = 0.f, Sei = 0.f, Me = 0.f;
        #pragma unroll
        for (int q = 0; q < 8; ++q) {
            Se  += red[q][row][0];
            Sei += red[q][row][1];
            Me   = fmaxf(Me, red[q][row][2]);
        }
        const int w1g = w1base + row;
        const float corresp = Sei / Se;            // soft-argmax (masked num, full denom)
        const float conf    = Me / Se;             // max of post-softmax masked prob
        float disp = fabsf(corresp - (float)w1g) * (1.0f / 512.0f);
        disp = fmaxf(disp, 0.1f);
        const float fx = intri1[b * 9];
        const float dx = extri1[b * 16 + 3]  - extri2[b * 16 + 3];
        const float dy = extri1[b * 16 + 7]  - extri2[b * 16 + 7];
        const float dz = extri1[b * 16 + 11] - extri2[b * 16 + 11];
        const float bl = sqrtf(dx * dx + dy * dy + dz * dz);
        const float depth = fx * bl / disp;
        const int oidx = b * HW + h * W_DIM + w1g;
        out[oidx]          = depth;
        out[2 * HW + oidx] = conf;                 // confidence block at B*H*W = 131072
    }
}

// ---------------- Fallback (R2 kernel, proven): direct f32 B loads, no ws
__global__ __launch_bounds__(512, 4) void costvol_fallback(
    const float* __restrict__ img1, const float* __restrict__ img2,
    const float* __restrict__ intri1,
    const float* __restrict__ extri1, const float* __restrict__ extri2,
    float* __restrict__ out)
{
    __shared__ __align__(16) unsigned char smem[32768];
    unsigned short* Alds = (unsigned short*)smem;
    const int t = threadIdx.x;
    const int d = blockIdx.x;
    const int win = d >> 6, pos = d & 63;
    const int bh    = win * 8 + (pos & 7);
    const int w1blk = pos >> 3;
    const int b = bh >> 7, h = bh & 127;
    const int w1base = w1blk * 64;
    const float* i1 = img1 + (size_t)b * CHW + (size_t)h * W_DIM;
    const float* i2 = img2 + (size_t)b * CHW + (size_t)h * W_DIM;
    {
        const int c    = t >> 1;
        const int wseg = (t & 1) << 5;
        const float* src = i1 + (size_t)c * HW + (size_t)(w1base + wseg);
        #pragma unroll
        for (int i0 = 0; i0 < 32; i0 += 4) {
            f32x4 v = *(const f32x4*)(src + i0);
            #pragma unroll
            for (int j = 0; j < 4; ++j) {
                const int w = wseg + i0 + j;
                Alds[w * 256 + ((((c >> 3) ^ (w & 15)) << 3) | (c & 7))] = f2bf(v[j]);
            }
        }
    }
    __syncthreads();
    const int wn = t >> 6, lane = t & 63;
    const int lrow = lane & 15, hq = lane >> 4;
    const float* pb[4];
    #pragma unroll
    for (int ct = 0; ct < 4; ++ct)
        pb[ct] = i2 + (size_t)(8 * hq) * HW + (64 * wn + 16 * ct + lrow);
    f32x4 acc[4][4] = {};
    for (int kc = 0; kc < 8; ++kc) {
        s16x8 afr[4];
        #pragma unroll
        for (int rt = 0; rt < 4; ++rt) {
            const int row = 16 * rt + lrow;
            const int kb  = (kc << 2) + hq;
            afr[rt] = *(const s16x8*)&Alds[row * 256 + ((kb ^ (row & 15)) << 3)];
        }
        #pragma unroll
        for (int ct = 0; ct < 4; ++ct) {
            const float* p = pb[ct] + (size_t)(32 * kc) * HW;
            float f[8];
            #pragma unroll
            for (int j = 0; j < 8; ++j) f[j] = p[(size_t)j * HW];
            s16x8 bfr;
            #pragma unroll
            for (int j = 0; j < 8; ++j) bfr[j] = (short)f2bf(f[j]);
            #pragma unroll
            for (int rt = 0; rt < 4; ++rt)
                acc[rt][ct] = __builtin_amdgcn_mfma_f32_16x16x32_bf16(afr[rt], bfr, acc[rt][ct], 0, 0, 0);
        }
    }
    __syncthreads();
    float (*red)[64][3] = (float(*)[64][3])smem;
    #pragma unroll
    for (int rt = 0; rt < 4; ++rt) {
        #pragma unroll
        for (int r = 0; r < 4; ++r) {
            const int row = 16 * rt + 4 * hq + r;
            const int w1g = w1base + row;
            float Se = 0.f, Sei = 0.f, Me = 0.f;
            #pragma unroll
            for (int ct = 0; ct < 4; ++ct) {
                const int col = 64 * wn + 16 * ct + lrow;
                const float e = __expf(acc[rt][ct][r] * 0.0625f);
                Se += e;
                if (col <= w1g) { Sei += e * (float)col; Me = fmaxf(Me, e); }
            }
            #pragma unroll
            for (int m = 1; m < 16; m <<= 1) {
                Se  += __shfl_xor(Se,  m, 64);
                Sei += __shfl_xor(Sei, m, 64);
                Me   = fmaxf(Me, __shfl_xor(Me, m, 64));
            }
            if (lrow == 0) { red[wn][row][0] = Se; red[wn][row][1] = Sei; red[wn][row][2] = Me; }
        }
    }
    __syncthreads();
    if (t < 64) {
        const int row = t;
        float Se = 0.f, Sei = 0.f, Me = 0.f;
        #pragma unroll
        for (int q = 0; q < 8; ++q) {
            Se += red[q][row][0]; Sei += red[q][row][1]; Me = fmaxf(Me, red[q][row][2]);
        }
        const int w1g = w1base + row;
        const float corresp = Sei / Se;
        const float conf    = Me / Se;
        float disp = fabsf(corresp - (float)w1g) * (1.0f / 512.0f);
        disp = fmaxf(disp, 0.1f);
        const float fx = intri1[b * 9];
        const float dx = extri1[b * 16 + 3]  - extri2[b * 16 + 3];
        const float dy = extri1[b * 16 + 7]  - extri2[b * 16 + 7];
        const float dz = extri1[b * 16 + 11] - extri2[b * 16 + 11];
        const float bl = sqrtf(dx * dx + dy * dy + dz * dz);
        const int oidx = b * HW + h * W_DIM + w1g;
        out[oidx]          = fx * bl / disp;
        out[2 * HW + oidx] = conf;
    }
}

extern "C" void kernel_launch(void* const* d_in, const int* in_sizes, int n_in,
                              void* d_out, int out_size, void* d_ws, size_t ws_size,
                              hipStream_t stream) {
    const float* img1   = (const float*)d_in[0];
    const float* img2   = (const float*)d_in[1];
    const float* intri1 = (const float*)d_in[2];
    const float* extri1 = (const float*)d_in[4];
    const float* extri2 = (const float*)d_in[5];
    if (ws_size >= WS_NEED) {
        unsigned short* bws = (unsigned short*)d_ws;
        transpose_kernel<<<dim3(8192), dim3(256), 0, stream>>>(img2, bws);
        costvol_kernel<<<dim3(2048), dim3(512), 0, stream>>>(
            img1, bws, intri1, extri1, extri2, (float*)d_out);
    } else {
        costvol_fallback<<<dim3(2048), dim3(512), 0, stream>>>(
            img1, img2, intri1, extri1, extri2, (float*)d_out);
    }
}

// Round 22
// 121.167 us; speedup vs baseline: 1.3733x; 1.0028x over previous
//
#include <hip/hip_runtime.h>
#include <hip/hip_bf16.h>

typedef __attribute__((ext_vector_type(4))) float f32x4;
typedef __attribute__((ext_vector_type(8))) short s16x8;

#define C_DIM 256
#define H_DIM 128
#define W_DIM 512
#define HW    (H_DIM * W_DIM)      /* 65536  */
#define CHW   (C_DIM * HW)         /* 16777216 */
#define WS_NEED (2ull * 128 * 512 * 256 * 2)   /* 67108864 B: bf16 [bh][n][k] */

__device__ __forceinline__ unsigned short f2bf(float f) {
    return __builtin_bit_cast(unsigned short, __float2bfloat16(f));
}

__device__ __forceinline__ void gl_lds16(const void* g, void* l) {
    __builtin_amdgcn_global_load_lds(
        (const __attribute__((address_space(1))) void*)g,
        (__attribute__((address_space(3))) void*)l, 16, 0, 0);
}

// ---------------- K1: transpose+convert img2 -> ws bf16 [bh][n=512][k=256] ----
// ~HBM-roofline: reads f32 coalesced, LDS-staged transpose, writes bf16
// k-contiguous.
__global__ __launch_bounds__(256) void transpose_kernel(
    const float* __restrict__ img2, unsigned short* __restrict__ bws)
{
    __shared__ unsigned short tile[64][65];
    const int t = threadIdx.x;
    const int d = blockIdx.x;               // 8192 = 2b*128h*4cb*8wb
    const int cb = d & 3, wb = (d >> 2) & 7, bh = d >> 5;
    const int b = bh >> 7, h = bh & 127;
    const float* src = img2 + (size_t)b * CHW + (size_t)h * W_DIM
                            + (size_t)(cb * 64) * HW + wb * 64;
    {
        const int c = t >> 2, w0 = (t & 3) << 4;
        const float* p = src + (size_t)c * HW + w0;
        #pragma unroll
        for (int i = 0; i < 16; i += 4) {
            f32x4 v = *(const f32x4*)(p + i);
            #pragma unroll
            for (int j = 0; j < 4; ++j) tile[c][w0 + i + j] = f2bf(v[j]);
        }
    }
    __syncthreads();
    {
        const int n_l = t >> 2, c4 = (t & 3) << 4;
        unsigned short vals[16];
        #pragma unroll
        for (int i = 0; i < 16; ++i) vals[i] = tile[c4 + i][n_l];
        unsigned short* dst = bws + ((size_t)bh * 512 + wb * 64 + n_l) * 256 + cb * 64 + c4;
        *(s16x8*)(dst)     = *(s16x8*)&vals[0];
        *(s16x8*)(dst + 8) = *(s16x8*)&vals[8];
    }
}

// ---------------- K2 (FINAL): 512 thr, 64 w1 x 512 w2, 8 waves of 64x64.
// LDS = A 32K + B 32K (wave-private single-buffer slices) -> 2 WGs/CU.
// XCD swizzle (T1) is ESSENTIAL: without it FETCH 100->434 MB (R20 A/B).
// No K-loop barriers: 8 independent per-wave pipelines; gl_lds B staging
// with split LDS drain (lgkmcnt(4)) + T5 setprio around the MFMA cluster.
// Swapped MFMA (D.row = w2): softmax axis lane-local -> cheap epilogue.
__global__ __launch_bounds__(512, 4) void costvol_kernel(
    const float* __restrict__ img1, const unsigned short* __restrict__ bws,
    const float* __restrict__ intri1,
    const float* __restrict__ extri1, const float* __restrict__ extri2,
    float* __restrict__ out)
{
    __shared__ __align__(16) unsigned char smem[65536];   // A 32K | B 32K
    unsigned short* Alds = (unsigned short*)smem;         // [64][256] bf16 swizzled

    const int t = threadIdx.x;
    const int d = blockIdx.x;                              // grid 2048
    // XCD swizzle: the 8 WGs sharing (b,h) get ids stride-8 apart -> same XCD
    const int win = d >> 6, pos = d & 63;
    const int bh    = win * 8 + (pos & 7);
    const int w1blk = pos >> 3;                            // 0..7
    const int b = bh >> 7, h = bh & 127;
    const int w1base = w1blk * 64;

    const int wv = t >> 6, lane = t & 63;
    const int lrow = lane & 15, hq = lane >> 4;

    // B staging, wave-private: wave wv owns w2 cols [64wv,64wv+64).
    // Slice = 64 rows x 32 k bf16 = 4KB; 4 gl_lds16 per kc. Source pre-swizzled
    // (m173 pattern): for u=i*64+lane: r=i*16+(lane>>2), k8=lane&3,
    // swz = (r>>1)&3 = (lane>>3)&3.
    const unsigned short* bsrc0 =
        bws + ((size_t)bh * 512 + 64 * wv + (lane >> 2)) * 256
            + 8 * ((lane & 3) ^ ((lane >> 3) & 3));
    unsigned char* const bdst = smem + 32768 + wv * 4096;   // wave slice base

    // prologue: issue B stage for kc=0 (in flight under A staging)
    #pragma unroll
    for (int i = 0; i < 4; ++i)
        gl_lds16(bsrc0 + i * 4096, bdst + i * 1024);

    // ---- stage A once, scaled by 1/16 (exact in bf16): [m=64][k=256],
    // 16B-block XOR swizzle
    const float* i1 = img1 + (size_t)b * CHW + (size_t)h * W_DIM;
    {
        const int c    = t >> 1;                 // 0..255
        const int wseg = (t & 1) << 5;           // 0 or 32
        const float* src = i1 + (size_t)c * HW + (size_t)(w1base + wseg);
        #pragma unroll
        for (int i0 = 0; i0 < 32; i0 += 4) {
            f32x4 v = *(const f32x4*)(src + i0);
            #pragma unroll
            for (int j = 0; j < 4; ++j) {
                const int w = wseg + i0 + j;
                Alds[w * 256 + ((((c >> 3) ^ (w & 15)) << 3) | (c & 7))] = f2bf(v[j] * 0.0625f);
            }
        }
    }
    __syncthreads();   // drains vmcnt too: B kc=0 landed + A visible to all waves

    f32x4 acc[4][4] = {};   // [w2t][w1t]

    // per-lane B read offsets (bytes) within this wave's 4KB slice:
    // local row = 16*w2t + lrow, k-group slot = hq ^ ((lrow>>1)&3)
    int boff[4];
    #pragma unroll
    for (int w2t = 0; w2t < 4; ++w2t)
        boff[w2t] = (16 * w2t + lrow) * 64 + 16 * (hq ^ ((lrow >> 1) & 3));

    #pragma unroll
    for (int kc = 0; kc < 8; ++kc) {
        // B-frag reads FIRST (their completion gates the DMA WAR) ...
        s16x8 bfr[4], afr[4];
        #pragma unroll
        for (int w2t = 0; w2t < 4; ++w2t)
            bfr[w2t] = *(const s16x8*)(bdst + boff[w2t]);
        // pin issue order: all 4 B-reads precede the A-reads
        __builtin_amdgcn_sched_barrier(0);
        #pragma unroll
        for (int w1t = 0; w1t < 4; ++w1t) {
            const int row = 16 * w1t + lrow;
            const int kb  = (kc << 2) + hq;
            afr[w1t] = *(const s16x8*)&Alds[row * 256 + ((kb ^ (row & 15)) << 3)];
        }
        // DS ops complete in-order: <=4 outstanding => the 4 B-reads landed.
        // (A-reads may still be in flight; the DMA only touches the B slice.)
        asm volatile("s_waitcnt lgkmcnt(4)" ::: "memory");
        __builtin_amdgcn_sched_barrier(0);
        // issue kc+1 DMA into the SAME wave-private slice (WAR safe)
        if (kc < 7) {
            #pragma unroll
            for (int i = 0; i < 4; ++i)
                gl_lds16(bsrc0 + (kc + 1) * 32 + i * 4096, bdst + i * 1024);
        }
        __builtin_amdgcn_sched_barrier(0);
        // MFMAs while the DMA flies; setprio favors the compute-phase wave
        // over co-resident staging-phase waves (independent pipelines -> T5 regime)
        __builtin_amdgcn_s_setprio(1);
        #pragma unroll
        for (int w2t = 0; w2t < 4; ++w2t)
            #pragma unroll
            for (int w1t = 0; w1t < 4; ++w1t)
                acc[w2t][w1t] = __builtin_amdgcn_mfma_f32_16x16x32_bf16(
                    bfr[w2t], afr[w1t], acc[w2t][w1t], 0, 0, 0);
        __builtin_amdgcn_s_setprio(0);
        // DMA must land before next iteration's slice reads
        if (kc < 7)
            asm volatile("s_waitcnt vmcnt(0)" ::: "memory");
    }

    __syncthreads();   // all waves done; A region reusable for reduction

    // ---- epilogue: lane-local over w2 (w2 = 64*wv + 16*w2t + 4*hq + r,
    //                w1 = 16*w1t + lrow), 2-step cross-hq butterfly.
    float (*red)[64][3] = (float(*)[64][3])smem;   // [8 waves][64 rows][Se,Sei,Me]
    #pragma unroll
    for (int w1t = 0; w1t < 4; ++w1t) {
        const int w1l = 16 * w1t + lrow;
        const int w1g = w1base + w1l;
        float Se = 0.f, Sei = 0.f, Me = 0.f;
        #pragma unroll
        for (int w2t = 0; w2t < 4; ++w2t) {
            #pragma unroll
            for (int r = 0; r < 4; ++r) {
                const int w2 = 64 * wv + 16 * w2t + 4 * hq + r;
                const float e = __expf(acc[w2t][w1t][r]);   // vol pre-scaled by 1/16
                Se += e;
                if (w2 <= w1g) { Sei += e * (float)w2; Me = fmaxf(Me, e); }
            }
        }
        Se  += __shfl_xor(Se, 16, 64);  Se  += __shfl_xor(Se, 32, 64);
        Sei += __shfl_xor(Sei, 16, 64); Sei += __shfl_xor(Sei, 32, 64);
        Me = fmaxf(Me, __shfl_xor(Me, 16, 64)); Me = fmaxf(Me, __shfl_xor(Me, 32, 64));
        if (hq == 0) {
            red[wv][w1l][0] = Se;
            red[wv][w1l][1] = Sei;
            red[wv][w1l][2] = Me;
        }
    }
    __syncthreads();

    if (t < 64) {
        const int row = t;
        float Se = 0.f, Sei = 0.f, Me = 0.f;
        #pragma unroll
        for (int q = 0; q < 8; ++q) {
            Se  += red[q][row][0];
            Sei += red[q][row][1];
            Me   = fmaxf(Me, red[q][row][2]);
        }
        const int w1g = w1base + row;
        const float corresp = Sei / Se;            // soft-argmax (masked num, full denom)
        const float conf    = Me / Se;             // max of post-softmax masked prob
        float disp = fabsf(corresp - (float)w1g) * (1.0f / 512.0f);
        disp = fmaxf(disp, 0.1f);
        const float fx = intri1[b * 9];
        const float dx = extri1[b * 16 + 3]  - extri2[b * 16 + 3];
        const float dy = extri1[b * 16 + 7]  - extri2[b * 16 + 7];
        const float dz = extri1[b * 16 + 11] - extri2[b * 16 + 11];
        const float bl = sqrtf(dx * dx + dy * dy + dz * dz);
        const float depth = fx * bl / disp;
        const int oidx = b * HW + h * W_DIM + w1g;
        out[oidx]          = depth;
        out[2 * HW + oidx] = conf;                 // confidence block at B*H*W = 131072
    }
}

// ---------------- Fallback (R2 kernel, proven): direct f32 B loads, no ws
__global__ __launch_bounds__(512, 4) void costvol_fallback(
    const float* __restrict__ img1, const float* __restrict__ img2,
    const float* __restrict__ intri1,
    const float* __restrict__ extri1, const float* __restrict__ extri2,
    float* __restrict__ out)
{
    __shared__ __align__(16) unsigned char smem[32768];
    unsigned short* Alds = (unsigned short*)smem;
    const int t = threadIdx.x;
    const int d = blockIdx.x;
    const int win = d >> 6, pos = d & 63;
    const int bh    = win * 8 + (pos & 7);
    const int w1blk = pos >> 3;
    const int b = bh >> 7, h = bh & 127;
    const int w1base = w1blk * 64;
    const float* i1 = img1 + (size_t)b * CHW + (size_t)h * W_DIM;
    const float* i2 = img2 + (size_t)b * CHW + (size_t)h * W_DIM;
    {
        const int c    = t >> 1;
        const int wseg = (t & 1) << 5;
        const float* src = i1 + (size_t)c * HW + (size_t)(w1base + wseg);
        #pragma unroll
        for (int i0 = 0; i0 < 32; i0 += 4) {
            f32x4 v = *(const f32x4*)(src + i0);
            #pragma unroll
            for (int j = 0; j < 4; ++j) {
                const int w = wseg + i0 + j;
                Alds[w * 256 + ((((c >> 3) ^ (w & 15)) << 3) | (c & 7))] = f2bf(v[j]);
            }
        }
    }
    __syncthreads();
    const int wn = t >> 6, lane = t & 63;
    const int lrow = lane & 15, hq = lane >> 4;
    const float* pb[4];
    #pragma unroll
    for (int ct = 0; ct < 4; ++ct)
        pb[ct] = i2 + (size_t)(8 * hq) * HW + (64 * wn + 16 * ct + lrow);
    f32x4 acc[4][4] = {};
    for (int kc = 0; kc < 8; ++kc) {
        s16x8 afr[4];
        #pragma unroll
        for (int rt = 0; rt < 4; ++rt) {
            const int row = 16 * rt + lrow;
            const int kb  = (kc << 2) + hq;
            afr[rt] = *(const s16x8*)&Alds[row * 256 + ((kb ^ (row & 15)) << 3)];
        }
        #pragma unroll
        for (int ct = 0; ct < 4; ++ct) {
            const float* p = pb[ct] + (size_t)(32 * kc) * HW;
            float f[8];
            #pragma unroll
            for (int j = 0; j < 8; ++j) f[j] = p[(size_t)j * HW];
            s16x8 bfr;
            #pragma unroll
            for (int j = 0; j < 8; ++j) bfr[j] = (short)f2bf(f[j]);
            #pragma unroll
            for (int rt = 0; rt < 4; ++rt)
                acc[rt][ct] = __builtin_amdgcn_mfma_f32_16x16x32_bf16(afr[rt], bfr, acc[rt][ct], 0, 0, 0);
        }
    }
    __syncthreads();
    float (*red)[64][3] = (float(*)[64][3])smem;
    #pragma unroll
    for (int rt = 0; rt < 4; ++rt) {
        #pragma unroll
        for (int r = 0; r < 4; ++r) {
            const int row = 16 * rt + 4 * hq + r;
            const int w1g = w1base + row;
            float Se = 0.f, Sei = 0.f, Me = 0.f;
            #pragma unroll
            for (int ct = 0; ct < 4; ++ct) {
                const int col = 64 * wn + 16 * ct + lrow;
                const float e = __expf(acc[rt][ct][r] * 0.0625f);
                Se += e;
                if (col <= w1g) { Sei += e * (float)col; Me = fmaxf(Me, e); }
            }
            #pragma unroll
            for (int m = 1; m < 16; m <<= 1) {
                Se  += __shfl_xor(Se,  m, 64);
                Sei += __shfl_xor(Sei, m, 64);
                Me   = fmaxf(Me, __shfl_xor(Me, m, 64));
            }
            if (lrow == 0) { red[wn][row][0] = Se; red[wn][row][1] = Sei; red[wn][row][2] = Me; }
        }
    }
    __syncthreads();
    if (t < 64) {
        const int row = t;
        float Se = 0.f, Sei = 0.f, Me = 0.f;
        #pragma unroll
        for (int q = 0; q < 8; ++q) {
            Se += red[q][row][0]; Sei += red[q][row][1]; Me = fmaxf(Me, red[q][row][2]);
        }
        const int w1g = w1base + row;
        const float corresp = Sei / Se;
        const float conf    = Me / Se;
        float disp = fabsf(corresp - (float)w1g) * (1.0f / 512.0f);
        disp = fmaxf(disp, 0.1f);
        const float fx = intri1[b * 9];
        const float dx = extri1[b * 16 + 3]  - extri2[b * 16 + 3];
        const float dy = extri1[b * 16 + 7]  - extri2[b * 16 + 7];
        const float dz = extri1[b * 16 + 11] - extri2[b * 16 + 11];
        const float bl = sqrtf(dx * dx + dy * dy + dz * dz);
        const int oidx = b * HW + h * W_DIM + w1g;
        out[oidx]          = fx * bl / disp;
        out[2 * HW + oidx] = conf;
    }
}

extern "C" void kernel_launch(void* const* d_in, const int* in_sizes, int n_in,
                              void* d_out, int out_size, void* d_ws, size_t ws_size,
                              hipStream_t stream) {
    const float* img1   = (const float*)d_in[0];
    const float* img2   = (const float*)d_in[1];
    const float* intri1 = (const float*)d_in[2];
    const float* extri1 = (const float*)d_in[4];
    const float* extri2 = (const float*)d_in[5];
    if (ws_size >= WS_NEED) {
        unsigned short* bws = (unsigned short*)d_ws;
        transpose_kernel<<<dim3(8192), dim3(256), 0, stream>>>(img2, bws);
        costvol_kernel<<<dim3(2048), dim3(512), 0, stream>>>(
            img1, bws, intri1, extri1, extri2, (float*)d_out);
    } else {
        costvol_fallback<<<dim3(2048), dim3(512), 0, stream>>>(
            img1, img2, intri1, extri1, extri2, (float*)d_out);
    }
}